// Round 2
// baseline (293.007 us; speedup 1.0000x reference)
//
#include <hip/hip_runtime.h>

constexpr int N_COLS = 16384;   // row length N
constexpr int HALF   = 8192;    // N/2 : half-size complex FFT length
constexpr int NT     = 1024;    // threads per block; 8 complex elements per thread

// Element-index swizzle for the float2 LDS array (bank pair = index mod 16).
// XOR-LINEAR: Sc(a^b) = Sc(a)^Sc(b); for bit-disjoint base/offset,
// Sc(base+off) = Sc(base)^Sc(off). Every access pattern below (scatter writes,
// three radix-8 rounds, four epilogue read streams) verified to hit exactly
// 4 lanes/bank-pair per b64 op = the structural minimum (512 B/instr floor).
__host__ __device__ constexpr int Sc(int p) {
    return p ^ ((p >> 4) & 15) ^ ((p >> 8) & 31);
}
// 3-bit reversal: position offset of the c-th element inside a thread's
// 8-consecutive-slot block after the bit-reversed scatter.
__host__ __device__ constexpr int br3(int c) {
    return ((c & 1) << 2) | (c & 2) | ((c & 4) >> 2);
}

// radix-2 DIT butterfly, twiddle 1
__device__ __forceinline__ void bf2(float2& a, float2& b) {
    float tr = b.x, ti = b.y;
    b.x = a.x - tr; b.y = a.y - ti;
    a.x += tr; a.y += ti;
}
// radix-2 DIT butterfly with twiddle (cw,sw) = e^{+j pi j2/(2*stride)} on b
__device__ __forceinline__ void bf2w(float2& a, float2& b, float cw, float sw) {
    float tr = cw * b.x - sw * b.y;
    float ti = cw * b.y + sw * b.x;
    b.x = a.x - tr; b.y = a.y - ti;
    a.x += tr; a.y += ti;
}
// radix-4 DIT butterfly on (e0,e1,e2,e3) at strides (0,s,2s,3s).
// w2 = (cw,sw) = e^{+j pi j/(2s)}; w1 = w2^2. Verbatim the verified butterfly.
__device__ __forceinline__ void bf4(float2& e0, float2& e1, float2& e2, float2& e3,
                                    float cw, float sw) {
    float c1 = cw * cw - sw * sw;
    float s1 = 2.0f * cw * sw;
    float tr, ti;
    tr = c1 * e1.x - s1 * e1.y; ti = c1 * e1.y + s1 * e1.x;
    e1.x = e0.x - tr; e1.y = e0.y - ti; e0.x += tr; e0.y += ti;
    tr = c1 * e3.x - s1 * e3.y; ti = c1 * e3.y + s1 * e3.x;
    e3.x = e2.x - tr; e3.y = e2.y - ti; e2.x += tr; e2.y += ti;
    tr = cw * e2.x - sw * e2.y; ti = cw * e2.y + sw * e2.x;
    e2.x = e0.x - tr; e2.y = e0.y - ti; e0.x += tr; e0.y += ti;
    tr = -sw * e3.x - cw * e3.y; ti = cw * e3.x - sw * e3.y;
    e3.x = e1.x - tr; e3.y = e1.y - ti; e1.x += tr; e1.y += ti;
}

// Fused radix-8 LDS round: radix-4 stage at stride S + radix-2 stage at 4S
// (run length S -> 8S). Thread owns the 8 elements base + S*c1 + 4S*c2,
// base = ((t & ~(S-1)) << 3) | (t & (S-1)) — read set == write set.
// Twiddles from expk (expk[n] = e^{-j pi n/32768}):
//   radix-4: j1 = base mod S,  w2 = e^{+j pi j1/(2S)}  -> n = j1*16384/S
//   radix-2: j2 = j1 + S*c1, angle pi*j2/(4S) -> n = j1*8192/S + 8192*c1;
//            c1>=2 exceeds the quarter-period table: e^{j(pi/2+phi)} = (e.y, e.x).
template<int S>
__device__ __forceinline__ void round8(float2* __restrict__ zs,
                                       const float2* __restrict__ ek2, int t) {
    const int j1 = t & (S - 1);
    const int sb = Sc(((t & ~(S - 1)) << 3) | j1);
    float2 v[2][4];
    #pragma unroll
    for (int c2 = 0; c2 < 2; ++c2)
        #pragma unroll
        for (int c1 = 0; c1 < 4; ++c1)
            v[c2][c1] = zs[sb ^ Sc(S * c1 + 4 * S * c2)];
    {
        float2 e = ek2[j1 * (16384 / S)];
        float cw = e.x, sw = -e.y;
        bf4(v[0][0], v[0][1], v[0][2], v[0][3], cw, sw);
        bf4(v[1][0], v[1][1], v[1][2], v[1][3], cw, sw);
    }
    #pragma unroll
    for (int c1 = 0; c1 < 4; ++c1) {
        float2 e = ek2[j1 * (8192 / S) + (c1 & 1) * 8192];
        float cw, sw;
        if (c1 < 2) { cw = e.x; sw = -e.y; }   // angle < pi/2: direct
        else        { cw = e.y; sw =  e.x; }   // angle >= pi/2: j-rotation
        bf2w(v[0][c1], v[1][c1], cw, sw);
    }
    #pragma unroll
    for (int c2 = 0; c2 < 2; ++c2)
        #pragma unroll
        for (int c1 = 0; c1 < 4; ++c1)
            zs[sb ^ Sc(S * c1 + 4 * S * c2)] = v[c2][c1];
}

// One block per row:
//   V_k = (x_k - j x_{N-k}) e^{j pi k/(2N)},  Z = half-size packing of V,
//   8192-pt complex IDFT of Z, y from re/im of z.
// 13 stages = in-register radix-8 fused into the scatter (thread's 8 values land
// in 8 consecutive bit-reversed slots) + three radix-8 LDS rounds (S=8,64,512)
// + span-4096 radix-2 fused into the epilogue. 4 barriers, 9 LDS traversals,
// all twiddles from the expk table, float4 coalesced stores.
__global__ __launch_bounds__(NT, 8)   // 8 waves/SIMD -> VGPR<=64, 2 blocks/CU
void idxct_kernel(const float* __restrict__ x,
                  const float* __restrict__ expk,
                  float* __restrict__ y)
{
    __shared__ float2 zs[HALF];   // 64 KiB

    const int row = blockIdx.x;
    const float* __restrict__ xr = x + (size_t)row * N_COLS;
    float* __restrict__ yr       = y + (size_t)row * N_COLS;
    const int t   = threadIdx.x;
    const float x0 = xr[0];
    const float2* __restrict__ ek2 = (const float2*)expk;

    // ---- scatter: Z_k for k = t + 1024c into regs at position offset br3(c) ----
    float2 v[8];
    #pragma unroll
    for (int c = 0; c < 8; ++c) {
        const int k = t + NT * c;
        float2 e0 = ek2[k];
        float c0 = e0.x, s0 = -e0.y;          // e^{+j pi k/(2N)}
        float vkr, vki;
        if (c == 0 && t == 0) { vkr = x0; vki = 0.0f; }
        else {
            float a = xr[k], b = xr[N_COLS - k];
            vkr = a * c0 + b * s0;            // (a - j b)(c + j s)
            vki = a * s0 - b * c0;
        }
        const int K = k + HALF;               // V_{k+H}
        float2 e1 = ek2[K];
        float c4 = e1.x, s4 = -e1.y;
        float a1 = xr[K], b1 = xr[N_COLS - K];
        float wkr = a1 * c4 + b1 * s4;
        float wki = a1 * s4 - b1 * c4;
        float dr = vkr - wkr, di = vki - wki;
        // e^{j 2 pi k/N} = (c0 + j s0)^4 (two complex squarings)
        float cA = c0 * c0 - s0 * s0, sA = 2.0f * c0 * s0;
        float ec = cA * cA - sA * sA, es = 2.0f * cA * sA;
        v[br3(c)] = make_float2((vkr + wkr) - (ec * di + es * dr),
                                (vki + wki) + (ec * dr - es * di));
    }

    // ---- in-register radix-8: stage s=1 (radix-2, tw 1) + s=2 (radix-4) ----
    // Verified by delta test: Z=delta_1 -> e^{2 pi i p/8}.
    bf2(v[0], v[1]); bf2(v[2], v[3]); bf2(v[4], v[5]); bf2(v[6], v[7]);
    bf4(v[0], v[2], v[4], v[6], 1.0f, 0.0f);              // j=0
    constexpr float RT = 0.70710678118654752440f;
    bf4(v[1], v[3], v[5], v[7], RT, RT);                  // j=1: e^{+j pi/4}

    // positions pb + o, pb = brev10(t)*8; Sc(pb+o) = Sc(pb)^o for o<16
    const int spb = Sc((int)(__brev((unsigned)t) >> 22) << 3);
    #pragma unroll
    for (int o = 0; o < 8; ++o) zs[spb ^ o] = v[o];

    // ---- three radix-8 LDS rounds: 8 -> 64 -> 512 -> 4096 ----
    __syncthreads();
    round8<8>(zs, ek2, t);
    __syncthreads();
    round8<64>(zs, ek2, t);
    __syncthreads();
    round8<512>(zs, ek2, t);
    __syncthreads();

    // ---- fused final radix-2 (stride 4096) + epilogue ----
    // z[m]      = u[m]      + w_m      * u[m+4096]
    // z[8191-m] = u[4095-m] - w_{4095-m} * u[8191-m]
    // y[4m] = re z[m], y[4m+1] = im z[8191-m], y[4m+2] = im z[m],
    // y[4m+3] = re z[8191-m]; all scaled 0.5*(.+x0). w_m = e^{+j pi m/4096}.
    {
        const int sct = Sc(t);
        const int scr = sct ^ Sc(1023);        // Sc(1023-t) = Sc(t^1023)
        #pragma unroll
        for (int i = 0; i < 4; ++i) {
            const int m  = t + NT * i;                     // [0, 4096)
            const int am = sct ^ Sc(NT * i);               // Sc(m)
            const int ar = scr ^ Sc(NT * (3 - i));         // Sc(4095 - m)
            float2 um = zs[am];
            float2 vm = zs[am ^ Sc(4096)];                 // Sc(m + 4096)
            float2 ur = zs[ar];
            float2 wr = zs[ar ^ Sc(4096)];                 // Sc(8191 - m)
            float cwm, swm, cwr, swr;
            if (i < 2) {                                   // m < 2048, r >= 2048
                float2 e = ek2[m << 3];
                cwm = e.x; swm = -e.y;
                float2 f = ek2[(2047 - m) << 3];           // r - 2048 = 2047 - m
                cwr = f.y; swr = f.x;
            } else {                                       // m >= 2048, r < 2048
                float2 e = ek2[(m - 2048) << 3];
                cwm = e.y; swm = e.x;
                float2 f = ek2[(4095 - m) << 3];
                cwr = f.x; swr = -f.y;
            }
            float trm = cwm * vm.x - swm * vm.y;
            float tim = cwm * vm.y + swm * vm.x;
            float trr = cwr * wr.x - swr * wr.y;
            float tir = cwr * wr.y + swr * wr.x;
            float4 o;
            o.x = 0.5f * ((um.x + trm) + x0);
            o.y = 0.5f * ((ur.y - tir) + x0);
            o.z = 0.5f * ((um.y + tim) + x0);
            o.w = 0.5f * ((ur.x - trr) + x0);
            *reinterpret_cast<float4*>(yr + 4 * m) = o;
        }
    }
}

extern "C" void kernel_launch(void* const* d_in, const int* in_sizes, int n_in,
                              void* d_out, int out_size, void* d_ws, size_t ws_size,
                              hipStream_t stream)
{
    const float* x    = (const float*)d_in[0];
    const float* expk = (const float*)d_in[1];
    float* y          = (float*)d_out;
    const int M = in_sizes[0] / N_COLS;        // 2048 rows
    idxct_kernel<<<dim3(M), dim3(NT), 0, stream>>>(x, expk, y);
}

// Round 4
// 269.071 us; speedup vs baseline: 1.0890x; 1.0890x over previous
//
#include <hip/hip_runtime.h>

constexpr int N_COLS = 16384;   // row length N
constexpr int HALF   = 8192;    // N/2 : half-size complex FFT length
constexpr int NT     = 1024;    // threads per block; 8 complex elements per thread

// Element-index swizzle for the float2 LDS array (bank pair = index mod 16).
// XOR-LINEAR: Sc(a^b) = Sc(a)^Sc(b); for bit-disjoint base/offset,
// Sc(base+off) = Sc(base)^Sc(off). All access patterns (scatter writes, three
// radix-8 rounds, four epilogue read streams) hit exactly 4 lanes/bank-pair
// per b64 op = the structural minimum (512 B/instr floor).
__host__ __device__ constexpr int Sc(int p) {
    return p ^ ((p >> 4) & 15) ^ ((p >> 8) & 31);
}
// 3-bit reversal: position offset of the c-th element inside a thread's
// 8-consecutive-slot block after the bit-reversed scatter.
__host__ __device__ constexpr int br3(int c) {
    return ((c & 1) << 2) | (c & 2) | ((c & 4) >> 2);
}

__device__ __forceinline__ float2 cmul(float2 a, float2 b) {
    return make_float2(a.x * b.x - a.y * b.y, a.x * b.y + a.y * b.x);
}

// radix-2 DIT butterfly, twiddle 1
__device__ __forceinline__ void bf2(float2& a, float2& b) {
    float tr = b.x, ti = b.y;
    b.x = a.x - tr; b.y = a.y - ti;
    a.x += tr; a.y += ti;
}
// radix-2 DIT butterfly with twiddle (cw,sw) on b
__device__ __forceinline__ void bf2w(float2& a, float2& b, float cw, float sw) {
    float tr = cw * b.x - sw * b.y;
    float ti = cw * b.y + sw * b.x;
    b.x = a.x - tr; b.y = a.y - ti;
    a.x += tr; a.y += ti;
}
// radix-4 DIT butterfly on (e0,e1,e2,e3) at strides (0,s,2s,3s).
// (cw,sw) = w2 = e^{+j pi j/(2s)}; w1 = w2^2. Verbatim the verified butterfly.
__device__ __forceinline__ void bf4(float2& e0, float2& e1, float2& e2, float2& e3,
                                    float cw, float sw) {
    float c1 = cw * cw - sw * sw;
    float s1 = 2.0f * cw * sw;
    float tr, ti;
    tr = c1 * e1.x - s1 * e1.y; ti = c1 * e1.y + s1 * e1.x;
    e1.x = e0.x - tr; e1.y = e0.y - ti; e0.x += tr; e0.y += ti;
    tr = c1 * e3.x - s1 * e3.y; ti = c1 * e3.y + s1 * e3.x;
    e3.x = e2.x - tr; e3.y = e2.y - ti; e2.x += tr; e2.y += ti;
    tr = cw * e2.x - sw * e2.y; ti = cw * e2.y + sw * e2.x;
    e2.x = e0.x - tr; e2.y = e0.y - ti; e0.x += tr; e0.y += ti;
    tr = -sw * e3.x - cw * e3.y; ti = cw * e3.x - sw * e3.y;
    e3.x = e1.x - tr; e3.y = e1.y - ti; e1.x += tr; e1.y += ti;
}

// Fused radix-8 LDS round: radix-4 stage at stride S + radix-2 stage at 4S.
// Thread owns elements base + S*c1 + 4S*c2 (read set == write set).
// E = e^{j theta}, theta = pi*j1/(4S), passed in REGISTERS (no memory access
// in here at all): radix-4 twiddle = E^2 (double angle); radix-2 twiddles are
// E rotated by c1*pi/4 (all derived with a few FMAs).
template<int S>
__device__ __forceinline__ void round8(float2* __restrict__ zs, int t, float2 E) {
    const int j1 = t & (S - 1);
    const int sb = Sc(((t & ~(S - 1)) << 3) | j1);
    float2 v[2][4];
    #pragma unroll
    for (int c2 = 0; c2 < 2; ++c2)
        #pragma unroll
        for (int c1 = 0; c1 < 4; ++c1)
            v[c2][c1] = zs[sb ^ Sc(S * c1 + 4 * S * c2)];
    {
        float cw = E.x * E.x - E.y * E.y;      // e^{j 2 theta}
        float sw = 2.0f * E.x * E.y;
        bf4(v[0][0], v[0][1], v[0][2], v[0][3], cw, sw);
        bf4(v[1][0], v[1][1], v[1][2], v[1][3], cw, sw);
    }
    constexpr float RT = 0.70710678118654752440f;
    float cA = (E.x - E.y) * RT;               // e^{j(theta + pi/4)}
    float sA = (E.x + E.y) * RT;
    bf2w(v[0][0], v[1][0],  E.x,  E.y);        // theta
    bf2w(v[0][1], v[1][1],  cA,   sA);         // theta + pi/4
    bf2w(v[0][2], v[1][2], -E.y,  E.x);        // theta + pi/2 (j-rotation)
    bf2w(v[0][3], v[1][3], -sA,   cA);         // theta + 3pi/4
    #pragma unroll
    for (int c2 = 0; c2 < 2; ++c2)
        #pragma unroll
        for (int c1 = 0; c1 < 4; ++c1)
            zs[sb ^ Sc(S * c1 + 4 * S * c2)] = v[c2][c1];
}

// One block per row:
//   V_k = (x_k - j x_{N-k}) e^{j pi k/(2N)},  Z = half-size packing of V,
//   8192-pt complex IDFT of Z, y from re/im of z.
// 13 stages = in-register radix-8 fused into the scatter + three radix-8 LDS
// rounds (S=8,64,512) + span-4096 radix-2 fused into the epilogue.
// ALL stage twiddles are built from 4 per-lane register constants (loaded once)
// x a wave-uniform broadcast factor — zero per-lane gathers inside the phases
// (the per-round strided table gathers were ~0.9 MB of L2 line traffic per
// block and the round-1/2 regression).
__global__ __launch_bounds__(NT, 8)   // 8 waves/SIMD -> VGPR<=64, 2 blocks/CU
void idxct_kernel(const float* __restrict__ x,
                  const float* __restrict__ expk,
                  float* __restrict__ y)
{
    __shared__ float2 zs[HALF];   // 64 KiB

    const int row = blockIdx.x;
    const float* __restrict__ xr = x + (size_t)row * N_COLS;
    float* __restrict__ yr       = y + (size_t)row * N_COLS;
    const int t   = threadIdx.x;
    const int l   = t & 63;        // lane
    const int wv  = t >> 6;        // wave index within block
    const float x0 = xr[0];
    const float2* __restrict__ ek2 = (const float2*)expk;

    // ---- one-time per-lane twiddle constants (expk[n] = e^{-j pi n/32768}) ----
    // E8    = e^{j pi (l&7)/32}   : theta for round S=8   (j1 = t&7 lane-local)
    // E64   = e^{j pi l/256}      : theta for round S=64  (j1 = t&63 = lane)
    // E512  = e^{j pi j1/2048}    : theta for round S=512, j1 = (wv&7)*64 + l
    // E4096 = e^{j pi l/4096}     : lane part of the epilogue twiddle
    float2 f;
    f = ek2[(l & 7) << 10];  const float2 E8    = make_float2(f.x, -f.y);
    f = ek2[l << 7];         const float2 E64   = make_float2(f.x, -f.y);
    f = ek2[l << 4];         float2 E512        = make_float2(f.x, -f.y);
    f = ek2[(wv & 7) << 10]; E512 = cmul(make_float2(f.x, -f.y), E512);
    f = ek2[l << 3];         const float2 E4096 = make_float2(f.x, -f.y);

    // ---- scatter: Z_k for k = t + 1024c into regs at position offset br3(c) ----
    float2 v[8];
    #pragma unroll
    for (int c = 0; c < 8; ++c) {
        const int k = t + NT * c;
        float2 e0 = ek2[k];
        float c0 = e0.x, s0 = -e0.y;          // e^{+j pi k/(2N)}
        float vkr, vki;
        if (c == 0 && t == 0) { vkr = x0; vki = 0.0f; }
        else {
            float a = xr[k], b = xr[N_COLS - k];
            vkr = a * c0 + b * s0;            // (a - j b)(c + j s)
            vki = a * s0 - b * c0;
        }
        const int K = k + HALF;               // V_{k+H}
        float2 e1 = ek2[K];
        float c4 = e1.x, s4 = -e1.y;
        float a1 = xr[K], b1 = xr[N_COLS - K];
        float wkr = a1 * c4 + b1 * s4;
        float wki = a1 * s4 - b1 * c4;
        float dr = vkr - wkr, di = vki - wki;
        // e^{j 2 pi k/N} = (c0 + j s0)^4 (two complex squarings)
        float cA = c0 * c0 - s0 * s0, sA = 2.0f * c0 * s0;
        float ec = cA * cA - sA * sA, es = 2.0f * cA * sA;
        v[br3(c)] = make_float2((vkr + wkr) - (ec * di + es * dr),
                                (vki + wki) + (ec * dr - es * di));
    }

    // ---- in-register radix-8: stage s=1 (radix-2, tw 1) + s=2 (radix-4) ----
    bf2(v[0], v[1]); bf2(v[2], v[3]); bf2(v[4], v[5]); bf2(v[6], v[7]);
    bf4(v[0], v[2], v[4], v[6], 1.0f, 0.0f);              // j=0
    constexpr float RT = 0.70710678118654752440f;
    bf4(v[1], v[3], v[5], v[7], RT, RT);                  // j=1: e^{+j pi/4}

    // positions pb + o, pb = brev10(t)*8; Sc(pb+o) = Sc(pb)^o for o<16
    const int spb = Sc((int)(__brev((unsigned)t) >> 22) << 3);
    #pragma unroll
    for (int o = 0; o < 8; ++o) zs[spb ^ o] = v[o];

    // ---- three radix-8 LDS rounds: 8 -> 64 -> 512 -> 4096 (no loads inside) ----
    __syncthreads();
    round8<8>(zs, t, E8);
    __syncthreads();
    round8<64>(zs, t, E64);
    __syncthreads();
    round8<512>(zs, t, E512);
    __syncthreads();

    // ---- fused final radix-2 (stride 4096) + epilogue ----
    // z[m]      = u[m]      + w_m        * u[m+4096],   w_m = e^{+j pi m/4096}
    // z[8191-m] = u[4095-m] - w_{4095-m} * u[8191-m]
    // y[4m]=re z[m], y[4m+1]=im z[8191-m], y[4m+2]=im z[m], y[4m+3]=re z[8191-m]
    // w_m = W(i,wv) x E4096[l]: broadcast (1 cacheline/wave) x lane register.
    // Reflected: e^{j pi (4095-m)/4096} = (-F.x, F.y), F = w_m * e^{j pi/4096}.
    {
        const float2 C4096 = make_float2(0.99999970586288222f,   // cos(pi/4096)
                                         7.6699031874270453e-4f);// sin(pi/4096)
        const int sct = Sc(t);
        const int scr = sct ^ Sc(1023);        // Sc(1023-t) = Sc(t^1023)
        #pragma unroll
        for (int i = 0; i < 4; ++i) {
            const int m  = t + NT * i;                     // [0, 4096)
            const int am = sct ^ Sc(NT * i);               // Sc(m)
            const int ar = scr ^ Sc(NT * (3 - i));         // Sc(4095 - m)
            float2 um = zs[am];
            float2 vm = zs[am ^ Sc(4096)];                 // Sc(m + 4096)
            float2 ur = zs[ar];
            float2 wr = zs[ar ^ Sc(4096)];                 // Sc(8191 - m)
            // wave part: angle pi*u/64, u = i*16 + wv in [0,64); u>=32 (i>=2)
            // exceeds the quarter-period table -> compile-time j-rotation.
            float2 fw = ek2[((i * 16 + wv) & 31) << 9];
            float2 W  = (i < 2) ? make_float2(fw.x, -fw.y)
                                : make_float2(fw.y,  fw.x);
            float2 Em = cmul(W, E4096);                    // e^{j pi m/4096}
            float2 F  = cmul(Em, C4096);
            float cwm = Em.x, swm = Em.y;
            float cwr = -F.x, swr = F.y;
            float trm = cwm * vm.x - swm * vm.y;
            float tim = cwm * vm.y + swm * vm.x;
            float trr = cwr * wr.x - swr * wr.y;
            float tir = cwr * wr.y + swr * wr.x;
            float4 o;
            o.x = 0.5f * ((um.x + trm) + x0);
            o.y = 0.5f * ((ur.y - tir) + x0);
            o.z = 0.5f * ((um.y + tim) + x0);
            o.w = 0.5f * ((ur.x - trr) + x0);
            *reinterpret_cast<float4*>(yr + 4 * m) = o;
        }
    }
}

extern "C" void kernel_launch(void* const* d_in, const int* in_sizes, int n_in,
                              void* d_out, int out_size, void* d_ws, size_t ws_size,
                              hipStream_t stream)
{
    const float* x    = (const float*)d_in[0];
    const float* expk = (const float*)d_in[1];
    float* y          = (float*)d_out;
    const int M = in_sizes[0] / N_COLS;        // 2048 rows
    idxct_kernel<<<dim3(M), dim3(NT), 0, stream>>>(x, expk, y);
}

// Round 5
// 254.317 us; speedup vs baseline: 1.1521x; 1.0580x over previous
//
#include <hip/hip_runtime.h>

#define PI_F 3.14159265358979323846f

constexpr int N_COLS = 16384;   // row length N
constexpr int HALF   = 8192;    // N/2 : half-size complex FFT length
constexpr int NT     = 1024;

// Bank swizzle (round-0 proven): folds addr bits 5..12 into bits 0..4.
// Bijective on [0,8192) and BIT-LINEAR: sw(a^b) = sw(a)^sw(b). For bit-disjoint
// base/offset splits, sw(base+off) = sw(base)^sw(off) with sw(off) a
// compile-time constant — 1 XOR per derived address instead of 6 ops.
__host__ __device__ constexpr int sw(int a) {
    return a ^ ((a >> 5) & 31) ^ ((a >> 10) & 31);
}
// 3-bit reversal for the scatter: brev13(t + 1024i) = (brev10(t)<<3) | br3(i)
__host__ __device__ constexpr int br3(int c) {
    return ((c & 1) << 2) | (c & 2) | ((c & 4) >> 2);
}

// One block per row (round-0 structure, streaming scatter, b32 split arrays):
//   V_k = (x_k - j x_{N-k}) e^{j pi k/(2N)}   (Hermitian, V_0 = x_0)
//   Z_k = (V_k + V_{k+H}) + j e^{j 2 pi k/N} (V_k - V_{k+H})  (half-size pack)
//   8192-pt complex IDFT in LDS: bit-reversed scatter + radix-4 passes
//   + final radix-2 FUSED into the float4-store epilogue.
// Twiddle scheme: in passes 1..5, j = q & (s-1) is u-invariant (1024 % s == 0),
// so each pass needs ONE per-thread twiddle -> 6 one-time __sincosf, zero
// table gathers in any phase (strided expk gathers were the round-1/2 regression).
__global__ __launch_bounds__(NT, 8)   // keep VGPR<=64 so LDS's 2 blocks/CU holds
void idxct_kernel(const float* __restrict__ x,
                  const float* __restrict__ expk,
                  float* __restrict__ y)
{
    __shared__ float sre[HALF];
    __shared__ float sim[HALF];

    const int row = blockIdx.x;
    const float* __restrict__ xr = x + (size_t)row * N_COLS;
    float* __restrict__ yr       = y + (size_t)row * N_COLS;
    const int t = threadIdx.x;
    const float x0 = xr[0];
    const float2* __restrict__ ek2 = (const float2*)expk;

    // ---- preprocess: Z_k -> LDS[sw(brev13(k))], k = t + 1024*i ----
    // Streaming: each Z written to LDS immediately (low register pressure so
    // the compiler keeps many of the 32 global loads in flight).
    const int spt = sw((int)(__brev((unsigned)t) >> 22) << 3);
    #pragma unroll
    for (int i = 0; i < HALF / NT; ++i) {
        int k = t + i * NT;
        float vkr, vki, c0, s0;
        {
            float2 e = ek2[k];
            c0 = e.x; s0 = -e.y;               // e^{+j pi k/(2N)}
            if (k == 0) { vkr = x0; vki = 0.0f; }
            else {
                float a = xr[k], b = xr[N_COLS - k];
                vkr = a * c0 + b * s0;         // (a - j b)(c + j s)
                vki = a * s0 - b * c0;
            }
        }
        float wkr, wki;                        // V_{k+H}
        {
            int K = k + HALF;
            float2 e = ek2[K];
            float c = e.x, s = -e.y;
            float a = xr[K], b = xr[N_COLS - K];
            wkr = a * c + b * s;
            wki = a * s - b * c;
        }
        float dr = vkr - wkr, di = vki - wki;
        // e^{j 2 pi k / N} = (c0 + j s0)^4  (two complex squarings)
        float cA = c0 * c0 - s0 * s0, sA = 2.0f * c0 * s0;
        float ec = cA * cA - sA * sA, es = 2.0f * cA * sA;
        float zr = (vkr + wkr) - (ec * di + es * dr);
        float zi = (vki + wki) + (ec * dr - es * di);
        int pa = spt ^ br3(i);                 // sw(brev13(k)), 1 XOR
        sre[pa] = zr;
        sim[pa] = zi;
    }

    // ---- one-time per-thread twiddles (TRANS pipe, overlaps barrier wait) ----
    // T[p-1] = e^{+j pi j / (2*4^p)}, j = t & (4^p - 1) — the pass-p twiddle,
    // identical for u=0,1. T6 = e^{+j pi t/4096} for the fused radix-2.
    float2 T[5], T6;
    {
        float sn, cs;
        __sincosf((float)(t & 3)   * (PI_F / 8.0f),    &sn, &cs); T[0] = make_float2(cs, sn);
        __sincosf((float)(t & 15)  * (PI_F / 32.0f),   &sn, &cs); T[1] = make_float2(cs, sn);
        __sincosf((float)(t & 63)  * (PI_F / 128.0f),  &sn, &cs); T[2] = make_float2(cs, sn);
        __sincosf((float)(t & 255) * (PI_F / 512.0f),  &sn, &cs); T[3] = make_float2(cs, sn);
        __sincosf((float)t         * (PI_F / 2048.0f), &sn, &cs); T[4] = make_float2(cs, sn);
        __sincosf((float)t         * (PI_F / 4096.0f), &sn, &cs); T6   = make_float2(cs, sn);
    }

    // ---- pass p=0 (s=1): twiddles are all 1 — pure butterflies (verbatim) ----
    __syncthreads();
    #pragma unroll
    for (int u = 0; u < 2; ++u) {
        int q = t + u * NT;
        int a0 = sw(q << 2);
        int a1 = a0 ^ 1, a2i = a0 ^ 2, a3 = a0 ^ 3;
        float r0 = sre[a0],  i0 = sim[a0];
        float r1 = sre[a1],  i1 = sim[a1];
        float r2 = sre[a2i], i2 = sim[a2i];
        float r3 = sre[a3],  i3 = sim[a3];
        float tr, ti;
        tr = r1;  ti = i1;  r1 = r0 - tr; i1 = i0 - ti; r0 += tr; i0 += ti;
        tr = r3;  ti = i3;  r3 = r2 - tr; i3 = i2 - ti; r2 += tr; i2 += ti;
        tr = r2;  ti = i2;  r2 = r0 - tr; i2 = i0 - ti; r0 += tr; i0 += ti;
        tr = -i3; ti = r3;  r3 = r1 - tr; i3 = i1 - ti; r1 += tr; i1 += ti;
        sre[a0]  = r0; sim[a0]  = i0;
        sre[a1]  = r1; sim[a1]  = i1;
        sre[a2i] = r2; sim[a2i] = i2;
        sre[a3]  = r3; sim[a3]  = i3;
    }

    // ---- passes p=1..5 (s=4..1024): register twiddle, XOR-derived addrs ----
    #pragma unroll
    for (int p = 1; p < 6; ++p) {
        const int s = 1 << (2 * p);
        __syncthreads();
        const float c2 = T[p - 1].x, s2 = T[p - 1].y;  // w2 = e^{+j pi j/(2s)}
        const float c1 = c2 * c2 - s2 * s2;            // w1 = w2^2
        const float s1 = 2.0f * c2 * s2;
        #pragma unroll
        for (int u = 0; u < 2; ++u) {
            int q = t + u * NT;
            int j = q & (s - 1);
            int base = ((q >> (2 * p)) << (2 * p + 2)) + j;
            int a0  = sw(base);
            int a1  = a0 ^ sw(s);              // compile-time constants
            int a2i = a0 ^ sw(2 * s);
            int a3  = a0 ^ sw(3 * s);
            float r0 = sre[a0],  i0 = sim[a0];
            float r1 = sre[a1],  i1 = sim[a1];
            float r2 = sre[a2i], i2 = sim[a2i];
            float r3 = sre[a3],  i3 = sim[a3];
            float tr, ti;
            tr = c1 * r1 - s1 * i1; ti = c1 * i1 + s1 * r1;
            r1 = r0 - tr; i1 = i0 - ti; r0 += tr; i0 += ti;
            tr = c1 * r3 - s1 * i3; ti = c1 * i3 + s1 * r3;
            r3 = r2 - tr; i3 = i2 - ti; r2 += tr; i2 += ti;
            tr = c2 * r2 - s2 * i2; ti = c2 * i2 + s2 * r2;
            r2 = r0 - tr; i2 = i0 - ti; r0 += tr; i0 += ti;
            tr = -s2 * r3 - c2 * i3; ti = c2 * r3 - s2 * i3;   // (j*w2)*e3
            r3 = r1 - tr; i3 = i1 - ti; r1 += tr; i1 += ti;
            sre[a0]  = r0; sim[a0]  = i0;
            sre[a1]  = r1; sim[a1]  = i1;
            sre[a2i] = r2; sim[a2i] = i2;
            sre[a3]  = r3; sim[a3]  = i3;
        }
    }
    __syncthreads();

    // ---- fused final radix-2 (stride 4096) + epilogue (verified r2/r4) ----
    // z[m]      = u[m]      + w_m        * u[m+4096],  w_m = e^{+j pi m/4096}
    // z[8191-m] = u[4095-m] - w_{4095-m} * u[8191-m]
    // y[4m]=re z[m], y[4m+1]=im z[8191-m], y[4m+2]=im z[m], y[4m+3]=re z[8191-m]
    // w_m = T6 rotated by i*pi/4 (compile-time); reflected twiddle
    // e^{j pi (4095-m)/4096} = (-F.x, F.y), F = w_m * e^{j pi/4096}.
    {
        const float2 C4 = make_float2(0.99999970586288222f,    // cos(pi/4096)
                                      7.6699031874270453e-4f); // sin(pi/4096)
        constexpr float RT = 0.70710678118654752440f;
        const int sct = sw(t);
        const int scr = sct ^ sw(1023);        // sw(1023-t) = sw(t^1023)
        #pragma unroll
        for (int i = 0; i < 4; ++i) {
            const int m   = t + NT * i;                    // [0, 4096)
            const int am  = sct ^ sw(NT * i);              // sw(m)
            const int ar  = scr ^ sw(NT * (3 - i));        // sw(4095 - m)
            const int am2 = am ^ sw(4096);                 // sw(m + 4096)
            const int ar2 = ar ^ sw(4096);                 // sw(8191 - m)
            float umr = sre[am],  umi = sim[am];
            float vmr = sre[am2], vmi = sim[am2];
            float urr = sre[ar],  uri = sim[ar];
            float wrr = sre[ar2], wri = sim[ar2];
            float exr, exi;                    // Em = T6 * e^{j i pi/4}
            if      (i == 0) { exr = T6.x;                 exi = T6.y; }
            else if (i == 1) { exr = (T6.x - T6.y) * RT;   exi = (T6.x + T6.y) * RT; }
            else if (i == 2) { exr = -T6.y;                exi = T6.x; }
            else             { exr = -(T6.x + T6.y) * RT;  exi = (T6.x - T6.y) * RT; }
            float Fr = exr * C4.x - exi * C4.y;
            float Fi = exr * C4.y + exi * C4.x;
            float cwr = -Fr, swr = Fi;         // e^{+j pi (4095-m)/4096}
            float trm = exr * vmr - exi * vmi;
            float tim = exr * vmi + exi * vmr;
            float trr = cwr * wrr - swr * wri;
            float tir = cwr * wri + swr * wrr;
            float4 o;
            o.x = 0.5f * ((umr + trm) + x0);
            o.y = 0.5f * ((uri - tir) + x0);
            o.z = 0.5f * ((umi + tim) + x0);
            o.w = 0.5f * ((urr - trr) + x0);
            *reinterpret_cast<float4*>(yr + 4 * m) = o;
        }
    }
}

extern "C" void kernel_launch(void* const* d_in, const int* in_sizes, int n_in,
                              void* d_out, int out_size, void* d_ws, size_t ws_size,
                              hipStream_t stream)
{
    const float* x    = (const float*)d_in[0];
    const float* expk = (const float*)d_in[1];
    float* y          = (float*)d_out;
    const int M = in_sizes[0] / N_COLS;        // 2048 rows
    idxct_kernel<<<dim3(M), dim3(NT), 0, stream>>>(x, expk, y);
}

// Round 6
// 252.223 us; speedup vs baseline: 1.1617x; 1.0083x over previous
//
#include <hip/hip_runtime.h>

#define PI_F 3.14159265358979323846f

constexpr int N_COLS = 16384;   // row length N
constexpr int HALF   = 8192;    // N/2 : half-size complex FFT length
constexpr int NT     = 1024;

// Swizzle on float2 ELEMENT indices (bank-pair = index & 15). XOR-LINEAR:
// Sc(a^b) = Sc(a)^Sc(b); for bit-disjoint base/offset, Sc(base+off) =
// Sc(base)^Sc(off) (compile-time). Verified per-phase: every wave access
// (scatter, pass0, passes 1-5, both epilogue streams) hits exactly 4 lanes
// per bank-pair = the b64 structural minimum. Measured 2.6e6 conflict cycles
// for this layout family (rounds 2/4) vs 8.4e6 for the b32 split arrays.
__host__ __device__ constexpr int Sc(int p) {
    return p ^ ((p >> 4) & 15) ^ ((p >> 8) & 31);
}
// 3-bit reversal for the scatter: brev13(t + 1024i) = (brev10(t)<<3) | br3(i)
__host__ __device__ constexpr int br3(int c) {
    return ((c & 1) << 2) | (c & 2) | ((c & 4) >> 2);
}

// One block per row (round-5 proven structure, LDS switched b32 -> float2):
//   V_k = (x_k - j x_{N-k}) e^{j pi k/(2N)}   (Hermitian, V_0 = x_0)
//   Z_k = (V_k + V_{k+H}) + j e^{j 2 pi k/N} (V_k - V_{k+H})  (half-size pack)
//   8192-pt complex IDFT in LDS: streaming bit-reversed scatter + radix-4
//   passes + final radix-2 FUSED into the float4-store epilogue.
// Twiddles: in passes 1..5, j = q & (s-1) is u-invariant (1024 % s == 0), so
// each pass needs ONE per-thread register twiddle -> 6 one-time __sincosf,
// zero table gathers in any phase.
__global__ __launch_bounds__(NT, 8)   // keep VGPR<=64; 2 blocks/CU (LDS-capped)
void idxct_kernel(const float* __restrict__ x,
                  const float* __restrict__ expk,
                  float* __restrict__ y)
{
    __shared__ float2 zs[HALF];   // 64 KiB

    const int row = blockIdx.x;
    const float* __restrict__ xr = x + (size_t)row * N_COLS;
    float* __restrict__ yr       = y + (size_t)row * N_COLS;
    const int t = threadIdx.x;
    const float x0 = xr[0];
    const float2* __restrict__ ek2 = (const float2*)expk;

    // ---- preprocess: Z_k -> zs[Sc(brev13(k))], k = t + 1024*i ----
    // Streaming: each Z written to LDS immediately (low register pressure so
    // the compiler keeps many of the 32 global loads in flight).
    const int spt = Sc((int)(__brev((unsigned)t) >> 22) << 3);
    #pragma unroll
    for (int i = 0; i < HALF / NT; ++i) {
        int k = t + i * NT;
        float vkr, vki, c0, s0;
        {
            float2 e = ek2[k];
            c0 = e.x; s0 = -e.y;               // e^{+j pi k/(2N)}
            if (k == 0) { vkr = x0; vki = 0.0f; }
            else {
                float a = xr[k], b = xr[N_COLS - k];
                vkr = a * c0 + b * s0;         // (a - j b)(c + j s)
                vki = a * s0 - b * c0;
            }
        }
        float wkr, wki;                        // V_{k+H}
        {
            int K = k + HALF;
            float2 e = ek2[K];
            float c = e.x, s = -e.y;
            float a = xr[K], b = xr[N_COLS - K];
            wkr = a * c + b * s;
            wki = a * s - b * c;
        }
        float dr = vkr - wkr, di = vki - wki;
        // e^{j 2 pi k / N} = (c0 + j s0)^4  (two complex squarings)
        float cA = c0 * c0 - s0 * s0, sA = 2.0f * c0 * s0;
        float ec = cA * cA - sA * sA, es = 2.0f * cA * sA;
        float zr = (vkr + wkr) - (ec * di + es * dr);
        float zi = (vki + wki) + (ec * dr - es * di);
        zs[spt ^ br3(i)] = make_float2(zr, zi);   // Sc(brev13(k)), 1 XOR
    }

    // ---- one-time per-thread twiddles (TRANS pipe, overlaps barrier wait) ----
    // T[p-1] = e^{+j pi j / (2*4^p)}, j = t & (4^p - 1) — the pass-p twiddle,
    // identical for u=0,1. T6 = e^{+j pi t/4096} for the fused radix-2.
    float2 T[5], T6;
    {
        float sn, cs;
        __sincosf((float)(t & 3)   * (PI_F / 8.0f),    &sn, &cs); T[0] = make_float2(cs, sn);
        __sincosf((float)(t & 15)  * (PI_F / 32.0f),   &sn, &cs); T[1] = make_float2(cs, sn);
        __sincosf((float)(t & 63)  * (PI_F / 128.0f),  &sn, &cs); T[2] = make_float2(cs, sn);
        __sincosf((float)(t & 255) * (PI_F / 512.0f),  &sn, &cs); T[3] = make_float2(cs, sn);
        __sincosf((float)t         * (PI_F / 2048.0f), &sn, &cs); T[4] = make_float2(cs, sn);
        __sincosf((float)t         * (PI_F / 4096.0f), &sn, &cs); T6   = make_float2(cs, sn);
    }

    // ---- pass p=0 (s=1): twiddles are all 1 — pure butterflies ----
    __syncthreads();
    #pragma unroll
    for (int u = 0; u < 2; ++u) {
        int q = t + u * NT;
        int a0 = Sc(q << 2);                   // low-2 bits clear, offsets <16:
        int a1 = a0 ^ 1, a2i = a0 ^ 2, a3 = a0 ^ 3;
        float2 e0 = zs[a0], e1 = zs[a1], e2 = zs[a2i], e3 = zs[a3];
        float tr, ti;
        tr = e1.x;  ti = e1.y;  e1.x = e0.x - tr; e1.y = e0.y - ti; e0.x += tr; e0.y += ti;
        tr = e3.x;  ti = e3.y;  e3.x = e2.x - tr; e3.y = e2.y - ti; e2.x += tr; e2.y += ti;
        tr = e2.x;  ti = e2.y;  e2.x = e0.x - tr; e2.y = e0.y - ti; e0.x += tr; e0.y += ti;
        tr = -e3.y; ti = e3.x;  e3.x = e1.x - tr; e3.y = e1.y - ti; e1.x += tr; e1.y += ti;
        zs[a0]  = e0; zs[a1] = e1; zs[a2i] = e2; zs[a3] = e3;
    }

    // ---- passes p=1..5 (s=4..1024): register twiddle, XOR-derived addrs ----
    #pragma unroll
    for (int p = 1; p < 6; ++p) {
        const int s = 1 << (2 * p);
        __syncthreads();
        const float c2 = T[p - 1].x, s2 = T[p - 1].y;  // w2 = e^{+j pi j/(2s)}
        const float c1 = c2 * c2 - s2 * s2;            // w1 = w2^2
        const float s1 = 2.0f * c2 * s2;
        #pragma unroll
        for (int u = 0; u < 2; ++u) {
            int q = t + u * NT;
            int j = q & (s - 1);
            int base = ((q >> (2 * p)) << (2 * p + 2)) + j;
            int a0  = Sc(base);
            int a1  = a0 ^ Sc(s);              // compile-time constants
            int a2i = a0 ^ Sc(2 * s);
            int a3  = a0 ^ Sc(3 * s);
            float2 e0 = zs[a0], e1 = zs[a1], e2 = zs[a2i], e3 = zs[a3];
            float tr, ti;
            tr = c1 * e1.x - s1 * e1.y; ti = c1 * e1.y + s1 * e1.x;
            e1.x = e0.x - tr; e1.y = e0.y - ti; e0.x += tr; e0.y += ti;
            tr = c1 * e3.x - s1 * e3.y; ti = c1 * e3.y + s1 * e3.x;
            e3.x = e2.x - tr; e3.y = e2.y - ti; e2.x += tr; e2.y += ti;
            tr = c2 * e2.x - s2 * e2.y; ti = c2 * e2.y + s2 * e2.x;
            e2.x = e0.x - tr; e2.y = e0.y - ti; e0.x += tr; e0.y += ti;
            tr = -s2 * e3.x - c2 * e3.y; ti = c2 * e3.x - s2 * e3.y;   // (j*w2)*e3
            e3.x = e1.x - tr; e3.y = e1.y - ti; e1.x += tr; e1.y += ti;
            zs[a0]  = e0; zs[a1] = e1; zs[a2i] = e2; zs[a3] = e3;
        }
    }
    __syncthreads();

    // ---- fused final radix-2 (stride 4096) + epilogue (verified r2/r4/r5) ----
    // z[m]      = u[m]      + w_m        * u[m+4096],  w_m = e^{+j pi m/4096}
    // z[8191-m] = u[4095-m] - w_{4095-m} * u[8191-m]
    // y[4m]=re z[m], y[4m+1]=im z[8191-m], y[4m+2]=im z[m], y[4m+3]=re z[8191-m]
    // w_m = T6 rotated by i*pi/4 (compile-time); reflected twiddle
    // e^{j pi (4095-m)/4096} = (-F.x, F.y), F = w_m * e^{j pi/4096}.
    {
        const float2 C4 = make_float2(0.99999970586288222f,    // cos(pi/4096)
                                      7.6699031874270453e-4f); // sin(pi/4096)
        constexpr float RT = 0.70710678118654752440f;
        const int sct = Sc(t);
        const int scr = sct ^ Sc(1023);        // Sc(1023-t) = Sc(t^1023)
        #pragma unroll
        for (int i = 0; i < 4; ++i) {
            const int m   = t + NT * i;                    // [0, 4096)
            const int am  = sct ^ Sc(NT * i);              // Sc(m)
            const int ar  = scr ^ Sc(NT * (3 - i));        // Sc(4095 - m)
            const int am2 = am ^ Sc(4096);                 // Sc(m + 4096)
            const int ar2 = ar ^ Sc(4096);                 // Sc(8191 - m)
            float2 um = zs[am];
            float2 vm = zs[am2];
            float2 ur = zs[ar];
            float2 wr = zs[ar2];
            float exr, exi;                    // Em = T6 * e^{j i pi/4}
            if      (i == 0) { exr = T6.x;                 exi = T6.y; }
            else if (i == 1) { exr = (T6.x - T6.y) * RT;   exi = (T6.x + T6.y) * RT; }
            else if (i == 2) { exr = -T6.y;                exi = T6.x; }
            else             { exr = -(T6.x + T6.y) * RT;  exi = (T6.x - T6.y) * RT; }
            float Fr = exr * C4.x - exi * C4.y;
            float Fi = exr * C4.y + exi * C4.x;
            float cwr = -Fr, swr = Fi;         // e^{+j pi (4095-m)/4096}
            float trm = exr * vm.x - exi * vm.y;
            float tim = exr * vm.y + exi * vm.x;
            float trr = cwr * wr.x - swr * wr.y;
            float tir = cwr * wr.y + swr * wr.x;
            float4 o;
            o.x = 0.5f * ((um.x + trm) + x0);
            o.y = 0.5f * ((ur.y - tir) + x0);
            o.z = 0.5f * ((um.y + tim) + x0);
            o.w = 0.5f * ((ur.x - trr) + x0);
            *reinterpret_cast<float4*>(yr + 4 * m) = o;
        }
    }
}

extern "C" void kernel_launch(void* const* d_in, const int* in_sizes, int n_in,
                              void* d_out, int out_size, void* d_ws, size_t ws_size,
                              hipStream_t stream)
{
    const float* x    = (const float*)d_in[0];
    const float* expk = (const float*)d_in[1];
    float* y          = (float*)d_out;
    const int M = in_sizes[0] / N_COLS;        // 2048 rows
    idxct_kernel<<<dim3(M), dim3(NT), 0, stream>>>(x, expk, y);
}

// Round 8
// 249.580 us; speedup vs baseline: 1.1740x; 1.0106x over previous
//
#include <hip/hip_runtime.h>

#define PI_F 3.14159265358979323846f

constexpr int N_COLS = 16384;   // row length N
constexpr int HALF   = 8192;    // N/2 : half-size complex FFT length
constexpr int NT     = 1024;

// Swizzle on float2 ELEMENT indices (bank-pair = index & 15). XOR-LINEAR:
// Sc(a^b) = Sc(a)^Sc(b); for bit-disjoint base/offset, Sc(base+off) =
// Sc(base)^Sc(off) (compile-time). Re-derived for the new stride set
// (8,32,128,512,2048) and both epilogue streams: every wave access hits
// exactly 4 lanes per bank-pair = the b64 structural minimum.
__host__ __device__ constexpr int Sc(int p) {
    return p ^ ((p >> 4) & 15) ^ ((p >> 8) & 31);
}
// 3-bit reversal for the scatter: brev13(t + 1024i) = (brev10(t)<<3) | br3(i)
__host__ __device__ constexpr int br3(int c) {
    return ((c & 1) << 2) | (c & 2) | ((c & 4) >> 2);
}

// radix-2 DIT butterfly, twiddle 1 (verbatim r2/r4-verified)
__device__ __forceinline__ void bf2(float2& a, float2& b) {
    float tr = b.x, ti = b.y;
    b.x = a.x - tr; b.y = a.y - ti;
    a.x += tr; a.y += ti;
}
// radix-4 DIT butterfly on (e0,e1,e2,e3) at strides (0,s,2s,3s).
// (cw,sw) = w2 = e^{+j pi j/(2s)}; w1 = w2^2 (internal double-angle).
// Verbatim the r2/r4/r6-verified butterfly.
__device__ __forceinline__ void bf4(float2& e0, float2& e1, float2& e2, float2& e3,
                                    float cw, float sw) {
    float c1 = cw * cw - sw * sw;
    float s1 = 2.0f * cw * sw;
    float tr, ti;
    tr = c1 * e1.x - s1 * e1.y; ti = c1 * e1.y + s1 * e1.x;
    e1.x = e0.x - tr; e1.y = e0.y - ti; e0.x += tr; e0.y += ti;
    tr = c1 * e3.x - s1 * e3.y; ti = c1 * e3.y + s1 * e3.x;
    e3.x = e2.x - tr; e3.y = e2.y - ti; e2.x += tr; e2.y += ti;
    tr = cw * e2.x - sw * e2.y; ti = cw * e2.y + sw * e2.x;
    e2.x = e0.x - tr; e2.y = e0.y - ti; e0.x += tr; e0.y += ti;
    tr = -sw * e3.x - cw * e3.y; ti = cw * e3.x - sw * e3.y;
    e3.x = e1.x - tr; e3.y = e1.y - ti; e1.x += tr; e1.y += ti;
}

// Radix-4 LDS pass at stride s = 1<<LS (covers stages s and 2s).
// w2 = (c2,s2) = e^{+j pi (t & (s-1)) / (2s)} — u-invariant for s <= 1024.
// ROT (s=2048 only): u=1 has j = t+1024 -> w2 rotated by e^{j pi/4}
// (compile-time constant rotation; w1 follows from the double-angle).
template<int LS, bool ROT>
__device__ __forceinline__ void pass4(float2* __restrict__ zs, int t,
                                      float c2, float s2) {
    const int s = 1 << LS;
    #pragma unroll
    for (int u = 0; u < 2; ++u) {
        float cw = c2, sw = s2;
        if (ROT && u == 1) {
            constexpr float RT = 0.70710678118654752440f;
            float cr = (cw - sw) * RT;
            float sr = (cw + sw) * RT;
            cw = cr; sw = sr;
        }
        int q = t + u * NT;
        int j = q & (s - 1);
        int base = ((q >> LS) << (LS + 2)) | j;
        int a0  = Sc(base);
        int a1  = a0 ^ Sc(s);                  // compile-time constants
        int a2i = a0 ^ Sc(2 * s);
        int a3  = a0 ^ Sc(3 * s);
        float2 e0 = zs[a0], e1 = zs[a1], e2 = zs[a2i], e3 = zs[a3];
        bf4(e0, e1, e2, e3, cw, sw);
        zs[a0] = e0; zs[a1] = e1; zs[a2i] = e2; zs[a3] = e3;
    }
}

// One block per row:
//   V_k = (x_k - j x_{N-k}) e^{j pi k/(2N)}   (Hermitian, V_0 = x_0)
//   Z_k = (V_k + V_{k+H}) + j e^{j 2 pi k/N} (V_k - V_{k+H})  (half-size pack)
//   8192-pt complex IDFT in LDS, y from re/im of z.
// 13 stages = streaming scatter + OWN-SLOT readback register radix-8 (stages
// 1,2,4 — no barrier: the thread's 8 scatter targets are its own 8 consecutive
// slots) + five radix-4 passes (s=8,32,128,512,2048) + pure-gather float4
// epilogue. 6 barriers, zero table gathers in any phase.
__global__ __launch_bounds__(NT, 8)   // keep VGPR<=64; 2 blocks/CU (LDS-capped)
void idxct_kernel(const float* __restrict__ x,
                  const float* __restrict__ expk,
                  float* __restrict__ y)
{
    __shared__ float2 zs[HALF];   // 64 KiB

    const int row = blockIdx.x;
    const float* __restrict__ xr = x + (size_t)row * N_COLS;
    float* __restrict__ yr       = y + (size_t)row * N_COLS;
    const int t = threadIdx.x;
    const float x0 = xr[0];
    const float2* __restrict__ ek2 = (const float2*)expk;

    // ---- preprocess: Z_k -> zs[Sc(brev13(k))], k = t + 1024*i ----
    // Streaming: each Z written to LDS immediately (low register pressure so
    // the compiler keeps many of the 32 global loads in flight).
    const int spt = Sc((int)(__brev((unsigned)t) >> 22) << 3);
    #pragma unroll
    for (int i = 0; i < HALF / NT; ++i) {
        int k = t + i * NT;
        float vkr, vki, c0, s0;
        {
            float2 e = ek2[k];
            c0 = e.x; s0 = -e.y;               // e^{+j pi k/(2N)}
            if (k == 0) { vkr = x0; vki = 0.0f; }
            else {
                float a = xr[k], b = xr[N_COLS - k];
                vkr = a * c0 + b * s0;         // (a - j b)(c + j s)
                vki = a * s0 - b * c0;
            }
        }
        float wkr, wki;                        // V_{k+H}
        {
            int K = k + HALF;
            float2 e = ek2[K];
            float c = e.x, s = -e.y;
            float a = xr[K], b = xr[N_COLS - K];
            wkr = a * c + b * s;
            wki = a * s - b * c;
        }
        float dr = vkr - wkr, di = vki - wki;
        // e^{j 2 pi k / N} = (c0 + j s0)^4  (two complex squarings)
        float cA = c0 * c0 - s0 * s0, sA = 2.0f * c0 * s0;
        float ec = cA * cA - sA * sA, es = 2.0f * cA * sA;
        float zr = (vkr + wkr) - (ec * di + es * dr);
        float zi = (vki + wki) + (ec * dr - es * di);
        zs[spt ^ br3(i)] = make_float2(zr, zi);   // Sc(brev13(k)), 1 XOR
    }

    // ---- own-slot readback + in-register radix-8 (stages s=1,2,4) ----
    // Thread reads back exactly the 8 slots it just wrote — no barrier, no
    // cross-thread dependency. Butterfly composition verbatim r2/r4 (verified
    // by delta test: Z=delta_1 -> e^{2 pi i p/8}).
    {
        float2 v[8];
        #pragma unroll
        for (int o = 0; o < 8; ++o) v[o] = zs[spt ^ o];   // position (brev10(t)<<3)+o
        bf2(v[0], v[1]); bf2(v[2], v[3]); bf2(v[4], v[5]); bf2(v[6], v[7]);
        constexpr float RT = 0.70710678118654752440f;
        bf4(v[0], v[2], v[4], v[6], 1.0f, 0.0f);          // j=0
        bf4(v[1], v[3], v[5], v[7], RT, RT);              // j=1: e^{+j pi/4}
        #pragma unroll
        for (int o = 0; o < 8; ++o) zs[spt ^ o] = v[o];
    }

    // ---- one-time per-thread twiddles (TRANS pipe; w2 = e^{j pi j/(2s)}) ----
    float2 T0, T1, T2, T3, T4;
    {
        float sn, cs;
        __sincosf((float)(t & 7)   * (PI_F / 16.0f),   &sn, &cs); T0 = make_float2(cs, sn);
        __sincosf((float)(t & 31)  * (PI_F / 64.0f),   &sn, &cs); T1 = make_float2(cs, sn);
        __sincosf((float)(t & 127) * (PI_F / 256.0f),  &sn, &cs); T2 = make_float2(cs, sn);
        __sincosf((float)(t & 511) * (PI_F / 1024.0f), &sn, &cs); T3 = make_float2(cs, sn);
        __sincosf((float)t         * (PI_F / 4096.0f), &sn, &cs); T4 = make_float2(cs, sn);
    }

    // ---- five radix-4 passes: 8 -> 32 -> 128 -> 512 -> 2048 -> 8192 ----
    __syncthreads();
    pass4<3,  false>(zs, t, T0.x, T0.y);
    __syncthreads();
    pass4<5,  false>(zs, t, T1.x, T1.y);
    __syncthreads();
    pass4<7,  false>(zs, t, T2.x, T2.y);
    __syncthreads();
    pass4<9,  false>(zs, t, T3.x, T3.y);
    __syncthreads();
    pass4<11, true >(zs, t, T4.x, T4.y);
    __syncthreads();

    // ---- epilogue: pure gather (FFT fully done), float4 coalesced stores ----
    // y[4m] = re z[m], y[4m+1] = im z[8191-m], y[4m+2] = im z[m],
    // y[4m+3] = re z[8191-m]; all 0.5*(. + x0).   8191-m = m^8191 (m<4096),
    // so Sc(8191-m) = Sc(m) ^ Sc(8191) — one XOR.
    {
        const int sct = Sc(t);
        #pragma unroll
        for (int i = 0; i < 4; ++i) {
            const int m  = t + NT * i;                 // [0, 4096)
            const int am = sct ^ Sc(NT * i);           // Sc(m)
            const int ao = am ^ Sc(8191);              // Sc(8191 - m)
            float2 zm = zs[am];
            float2 zo = zs[ao];
            float4 o;
            o.x = 0.5f * (zm.x + x0);
            o.y = 0.5f * (zo.y + x0);
            o.z = 0.5f * (zm.y + x0);
            o.w = 0.5f * (zo.x + x0);
            *reinterpret_cast<float4*>(yr + 4 * m) = o;
        }
    }
}

extern "C" void kernel_launch(void* const* d_in, const int* in_sizes, int n_in,
                              void* d_out, int out_size, void* d_ws, size_t ws_size,
                              hipStream_t stream)
{
    const float* x    = (const float*)d_in[0];
    const float* expk = (const float*)d_in[1];
    float* y          = (float*)d_out;
    const int M = in_sizes[0] / N_COLS;        // 2048 rows
    idxct_kernel<<<dim3(M), dim3(NT), 0, stream>>>(x, expk, y);
}